// Round 10
// baseline (223.613 us; speedup 1.0000x reference)
//
#include <hip/hip_runtime.h>
#include <hip/hip_bf16.h>

#define DEV static __device__ __forceinline__

typedef short s8v __attribute__((ext_vector_type(8)));
typedef float f16v __attribute__((ext_vector_type(16)));
typedef unsigned short u16;
typedef unsigned int u32;

constexpr int IMG = 1024;            // B*N
constexpr int IE  = 1600;            // 64ch * 25pix
constexpr float INV_TEMP = 0.035355339059327376f;

// ---- bf16 weight region (ushort offsets), k-major layout [o][k]
constexpr int WU = 0, WV = 36864, WSELF = 73728, WAFF = 110592,
              WAGA = 147456, WAGS = 184320;          // 64x576 each (k=t*64+c)
constexpr int WQ = 221184, WK = 230400;              // 32x288 each (k=t*32+c)
constexpr int WATT = 239616;                         // 32x64 (k=c)
// ---- float offsets in ws (start past 241664 u16 = 120832 f32)
constexpr size_t OFF_Q    = 120832;                  // 1024*800
constexpr size_t OFF_K    = OFF_Q + 819200;
constexpr size_t OFF_U    = OFF_Q;                   // alias: Q,K dead after k2
constexpr size_t OFF_V    = OFF_Q + 1638400;
constexpr size_t OFF_XS   = OFF_V + 1638400;
constexpr size_t OFF_A    = OFF_XS + 1638400;
constexpr size_t OFF_SM   = OFF_A + 1638400;         // 64*256
constexpr size_t OFF_SUMS = OFF_SM + 16384;          // 128

DEV u16 f2bf(float f) {
  u32 u = __float_as_uint(f);
  return (u16)((u + 0x7FFF + ((u >> 16) & 1)) >> 16);
}
DEV int xrow(int p) { return (p / 5 + 1) * 8 + (p % 5 + 1); }
DEV int slotOf(int R) { return (3 * (R >> 3) + (R & 7)) & 7; }
DEV f16v zero16() {
  f16v z;
#pragma unroll
  for (int i = 0; i < 16; ++i) z[i] = 0.f;
  return z;
}
// write channel-pair (c=2cp, 2cp+1) of pixel p as packed bf16 into swizzled xT
DEV void xt_write_pair(u16* xt, int p, int cp, float v0, float v1) {
  int R = xrow(p);
  int chunk = ((cp >> 2) ^ slotOf(R)) & 7;
  u32 u = (u32)f2bf(v0) | ((u32)f2bf(v1) << 16);
  *(u32*)((char*)xt + R * 128 + chunk * 16 + (cp & 3) * 4) = u;
}
// per-lane, per-tap base byte offsets into a 7x8x64ch swizzled xT image
DEV void mk_bases(int lane, int bases[9]) {
  int p = lane & 31; if (p > 24) p = 24;       // cols 25-31: clamped (discarded)
  int hi = lane >> 5;
  int y = p / 5, x = p % 5;
#pragma unroll
  for (int t = 0; t < 9; ++t) {
    int R = (y + t / 3) * 8 + (x + t % 3);
    int sl = slotOf(R);
    bases[t] = R * 128 + (((sl ^ hi) & 7) << 4);
  }
}

// ---------------- K0: weight prep (bf16 k-major) -----------------------------
__global__ __launch_bounds__(256) void k0_prep(
    const float* __restrict__ w_rel, const float* __restrict__ w_self,
    const float* __restrict__ w_aff, const float* __restrict__ w_agg,
    const float* __restrict__ w_q, const float* __restrict__ w_k,
    const float* __restrict__ w_attn, float* __restrict__ ws) {
  u16* wb = (u16*)ws;
  int idx = blockIdx.x * 256 + threadIdx.x;
  if (idx < 221184) {
    int reg = idx / 36864, w = idx % 36864;
    int o = w / 576, k = w % 576, t = k >> 6, c = k & 63;
    float v;
    switch (reg) {
      case 0:  v = w_rel[(o * 128 + c) * 9 + t]; break;
      case 1:  v = w_rel[(o * 128 + 64 + c) * 9 + t]; break;
      case 2:  v = w_self[(o * 64 + c) * 9 + t]; break;
      case 3:  v = w_aff[(o * 64 + c) * 9 + t]; break;
      case 4:  v = w_agg[(o * 128 + c) * 9 + t]; break;
      default: v = w_agg[(o * 128 + 64 + c) * 9 + t]; break;
    }
    wb[idx] = f2bf(v);
  } else if (idx < 239616) {
    int i2 = idx - 221184;
    int conv = i2 / 9216, r = i2 % 9216;
    int o = r / 288, k = r % 288, t = k >> 5, c = k & 31;
    const float* src = conv ? w_k : w_q;
    wb[idx] = f2bf(src[(o * 32 + c) * 9 + t]);
  } else if (idx < 241664) {
    wb[idx] = f2bf(w_attn[idx - 239616]);   // [ds][c], k=c already k-major
  }
}

// ---------------- K1: s2d (MFMA) + q/k 3x3 convs (MFMA); 2 img/block ---------
__global__ __launch_bounds__(256, 2) void k1_qk(
    const float* __restrict__ x, const float* __restrict__ b_attn,
    const float* __restrict__ b_q, const float* __restrict__ b_k,
    float* __restrict__ ws) {
  __shared__ float xlin[3200];
  __shared__ u16 xtx[2 * 3584];     // swizzled x (64ch)
  __shared__ u16 xts[2 * 3584];     // swizzled s2d (32ch, chunks 0-3)
  __shared__ float batt[32];
  const u16* wb = (const u16*)ws;
  int tid = threadIdx.x, lane = tid & 63, wave = tid >> 6, hi = lane >> 5;
  int img0 = blockIdx.x * 2;
  int conv = wave & 1, wimg = wave >> 1;
  int oA = lane & 31;
  const u16* wsrc = wb + (conv ? WK : WQ) + oA * 288 + hi * 8;
  s8v Aq[18];
#pragma unroll
  for (int s = 0; s < 18; ++s) Aq[s] = *(const s8v*)(wsrc + s * 16);
  const u16* wa = wb + WATT + oA * 64 + hi * 8;
  s8v As[4];
#pragma unroll
  for (int s = 0; s < 4; ++s) As[s] = *(const s8v*)(wa + s * 16);
  int bases[9]; mk_bases(lane, bases);
  for (int i = tid; i < 3200; i += 256) xlin[i] = x[(size_t)img0 * IE + i];
  if (tid < 32) batt[tid] = b_attn[tid];
  // zero FULL buffers: each 2*3584 u16 = 3584 u32 (R7 bug: was 1792 -> img1 halo stale-LDS)
  for (int i = tid; i < 3584; i += 256) { ((u32*)xtx)[i] = 0; ((u32*)xts)[i] = 0; }
  __syncthreads();
  for (int i = tid; i < 1600; i += 256) {          // pack x -> xtx (both imgs)
    int im = i / 800, r = i % 800, p = r >> 5, cp = r & 31;
    xt_write_pair(xtx + im * 3584, p, cp,
                  xlin[im * 1600 + cp * 50 + p], xlin[im * 1600 + cp * 50 + 25 + p]);
  }
  __syncthreads();
  // s2d: 1x1 conv, K=64, tap center (t=4)
  f16v sacc = zero16();
  const char* xbx = (const char*)xtx + wimg * 7168;
#pragma unroll
  for (int s = 0; s < 4; ++s) {
    s8v bfr = *(const s8v*)(xbx + (bases[4] ^ (s << 5)));
    sacc = __builtin_amdgcn_mfma_f32_32x32x16_bf16(As[s], bfr, sacc, 0, 0, 0);
  }
  int p = lane & 31;
  if (conv == 0 && p < 25) {          // one wave per img packs s2d (+bias)
#pragma unroll
    for (int a = 0; a < 8; ++a) {
      int r0 = 2 * a;
      int ds0 = (r0 & 3) + 8 * (r0 >> 2) + 4 * hi;
      xt_write_pair(xts + wimg * 3584, p, ds0 >> 1,
                    sacc[r0] + batt[ds0], sacc[r0 + 1] + batt[ds0 + 1]);
    }
  }
  __syncthreads();
  f16v acc = zero16();
  const char* xbs = (const char*)xts + wimg * 7168;
#pragma unroll
  for (int s = 0; s < 18; ++s) {
    s8v bfr = *(const s8v*)(xbs + (bases[s >> 1] ^ ((s & 1) << 5)));
    acc = __builtin_amdgcn_mfma_f32_32x32x16_bf16(Aq[s], bfr, acc, 0, 0, 0);
  }
  float* outp = ws + (conv ? OFF_K : OFF_Q) + (size_t)(img0 + wimg) * 800;
  const float* bq = conv ? b_k : b_q;
  if (p < 25) {
#pragma unroll
    for (int r = 0; r < 16; ++r) {
      int ol = (r & 3) + 8 * (r >> 2) + 4 * hi;
      outp[ol * 25 + p] = fmaxf(acc[r] + bq[ol], 0.f);
    }
  }
}

// ---------------- K2: attn logits + softmax (+ zero LN sums) -----------------
__global__ __launch_bounds__(1024) void k2_attn(float* __restrict__ ws) {
  __shared__ float kb[16][804];
  __shared__ float att[16][17];
  __shared__ float rowm[16], rowsum[16];
  int b = blockIdx.x, tid = threadIdx.x;
  const float* kg = ws + OFF_K + (size_t)b * 12800;
  for (int i = tid; i < 12800; i += 1024) kb[i / 800][i % 800] = kg[i];
  if (tid < 2) ws[OFF_SUMS + b * 2 + tid] = 0.f;
  __syncthreads();
  int pair = tid >> 2, sub = tid & 3;
  int i = pair >> 4, j = pair & 15;
  const float* qr = ws + OFF_Q + (size_t)(b * 16 + i) * 800;
  float acc = 0.f;
  for (int f = sub * 4; f < 800; f += 16) {
    float4 a = *(const float4*)(qr + f);
    float4 c = *(const float4*)&kb[j][f];
    acc += a.x * c.x + a.y * c.y + a.z * c.z + a.w * c.w;
  }
  acc += __shfl_xor(acc, 1, 64);
  acc += __shfl_xor(acc, 2, 64);
  if (sub == 0) att[i][j] = acc * INV_TEMP;
  __syncthreads();
  if (tid < 16) {
    float m = att[tid][0];
    for (int jj = 1; jj < 16; ++jj) m = fmaxf(m, att[tid][jj]);
    float s = 0.f;
    for (int jj = 0; jj < 16; ++jj) s += expf(att[tid][jj] - m);
    rowm[tid] = m; rowsum[tid] = 1.f / s;
  }
  __syncthreads();
  if (tid < 256) {
    int ii = tid >> 4, jj = tid & 15;
    ws[OFF_SM + (size_t)b * 256 + tid] = expf(att[ii][jj] - rowm[ii]) * rowsum[ii];
  }
}

// ---------------- K3: u, v, xs convs via MFMA; 2 img/block, 6 waves ----------
__global__ __launch_bounds__(384, 2) void k3_uvxs(
    const float* __restrict__ x, const float* __restrict__ b_rel,
    const float* __restrict__ b_self, float* __restrict__ ws) {
  __shared__ float xlin[1600];
  __shared__ u16 xt[3584];
  const u16* wb = (const u16*)ws;
  int tid = threadIdx.x, lane = tid & 63, wave = tid >> 6, hi = lane >> 5;
  int conv = wave >> 1, ot = wave & 1;     // conv: 0=u 1=v 2=self
  int oA = ot * 32 + (lane & 31);
  const u16* wsrc = wb + (conv == 0 ? WU : (conv == 1 ? WV : WSELF)) + oA * 576 + hi * 8;
  s8v A[36];
#pragma unroll
  for (int s = 0; s < 36; ++s) A[s] = *(const s8v*)(wsrc + s * 16);
  int bases[9]; mk_bases(lane, bases);
  for (int i = tid; i < 1792; i += 384) ((u32*)xt)[i] = 0;   // 3584 u16 = 1792 u32 ✓ full
  int img0 = blockIdx.x * 2;
  size_t obase = conv == 0 ? OFF_U : (conv == 1 ? OFF_V : OFF_XS);
  for (int im = 0; im < 2; ++im) {
    int img = img0 + im;
    __syncthreads();
    for (int i = tid; i < 1600; i += 384) xlin[i] = x[(size_t)img * IE + i];
    __syncthreads();
    for (int i = tid; i < 800; i += 384) {
      int p = i >> 5, cp = i & 31;
      xt_write_pair(xt, p, cp, xlin[cp * 50 + p], xlin[cp * 50 + 25 + p]);
    }
    __syncthreads();
    f16v acc = zero16();
#pragma unroll
    for (int s = 0; s < 36; ++s) {
      s8v bfr = *(const s8v*)((const char*)xt + (bases[s >> 2] ^ ((s & 3) << 5)));
      acc = __builtin_amdgcn_mfma_f32_32x32x16_bf16(A[s], bfr, acc, 0, 0, 0);
    }
    int p = lane & 31;
    if (p < 25) {
      float* outp = ws + obase + (size_t)img * IE;
#pragma unroll
      for (int r = 0; r < 16; ++r) {
        int ol = ot * 32 + (r & 3) + 8 * (r >> 2) + 4 * hi;
        float v = acc[r];
        if (conv == 1) v += b_rel[ol];
        if (conv == 2) v = fmaxf(v + b_self[ol], 0.f);
        outp[ol * 25 + p] = v;
      }
    }
  }
}

// ---------------- K5: pred combine + aff conv (MFMA) + a + LN sums -----------
__global__ __launch_bounds__(256, 2) void k5_pred_aff(
    const float* __restrict__ x, const float* __restrict__ b_aff,
    float* __restrict__ ws) {
  __shared__ float predlin[2][1600];
  __shared__ u16 xt[2][3584];
  __shared__ float smr[2][16];
  __shared__ float selfw[2];
  const u16* wb = (const u16*)ws;
  int tid = threadIdx.x, lane = tid & 63, wave = tid >> 6, hi = lane >> 5;
  int img0 = blockIdx.x * 2, bat = img0 >> 4;
  int wimg = wave >> 1, ot = wave & 1;
  int oA = ot * 32 + (lane & 31);
  const u16* wsrc = wb + WAFF + oA * 576 + hi * 8;
  s8v A[36];
#pragma unroll
  for (int s = 0; s < 36; ++s) A[s] = *(const s8v*)(wsrc + s * 16);
  int bases[9]; mk_bases(lane, bases);
  for (int i = tid; i < 3584; i += 256) ((u32*)&xt[0][0])[i] = 0;  // 2*3584 u16 ✓ full
  if (tid < 32) { int k = tid >> 4, j = tid & 15; smr[k][j] = ws[OFF_SM + (size_t)(img0 + k) * 16 + j]; }
  if (tid < 2)  { int n = (img0 + tid) & 15; selfw[tid] = ws[OFF_SM + (size_t)(img0 + tid) * 16 + n]; }
  __syncthreads();
  const float* U = ws + OFF_U; const float* V = ws + OFF_V; const float* XS = ws + OFF_XS;
  for (int i4 = tid; i4 < 800; i4 += 256) {
    int im = i4 / 400, e = (i4 % 400) * 4;
    size_t gi = (size_t)(img0 + im) * IE + e;
    float4 uu = *(const float4*)(U + gi);
    float4 xx = *(const float4*)(XS + gi);
    float sw = selfw[im];
    int nk = (img0 + im) & 15;
    float ax = sw * xx.x, ay = sw * xx.y, az = sw * xx.z, aw = sw * xx.w;
#pragma unroll
    for (int j = 0; j < 16; ++j) {
      float wj = (j == nk) ? 0.f : smr[im][j];
      float4 vv = *(const float4*)(V + (size_t)(bat * 16 + j) * IE + e);
      ax = fmaf(wj, fmaxf(uu.x + vv.x, 0.f), ax);
      ay = fmaf(wj, fmaxf(uu.y + vv.y, 0.f), ay);
      az = fmaf(wj, fmaxf(uu.z + vv.z, 0.f), az);
      aw = fmaf(wj, fmaxf(uu.w + vv.w, 0.f), aw);
    }
    *(float4*)&predlin[im][e] = make_float4(ax, ay, az, aw);
  }
  __syncthreads();
  for (int i = tid; i < 1600; i += 256) {
    int im = i / 800, r = i % 800, p = r >> 5, cp = r & 31;
    xt_write_pair(&xt[im][0], p, cp, predlin[im][cp * 50 + p], predlin[im][cp * 50 + 25 + p]);
  }
  __syncthreads();
  f16v acc = zero16();
  const char* xb = (const char*)&xt[wimg][0];
#pragma unroll
  for (int s = 0; s < 36; ++s) {
    s8v bfr = *(const s8v*)(xb + (bases[s >> 2] ^ ((s & 3) << 5)));
    acc = __builtin_amdgcn_mfma_f32_32x32x16_bf16(A[s], bfr, acc, 0, 0, 0);
  }
  int p = lane & 31;
  float s1 = 0.f, s2 = 0.f;
  float* aout = ws + OFF_A + (size_t)(img0 + wimg) * IE;
  const float* xg = x + (size_t)(img0 + wimg) * IE;
  if (p < 25) {
#pragma unroll
    for (int r = 0; r < 16; ++r) {
      int ol = ot * 32 + (r & 3) + 8 * (r >> 2) + 4 * hi;
      float a = fmaxf(acc[r] + b_aff[ol], 0.f) + xg[ol * 25 + p];
      aout[ol * 25 + p] = a;
      s1 += a; s2 = fmaf(a, a, s2);
    }
  }
  for (int off = 32; off; off >>= 1) {
    s1 += __shfl_down(s1, off, 64);
    s2 += __shfl_down(s2, off, 64);
  }
  if (lane == 0) {
    atomicAdd(ws + OFF_SUMS + bat * 2, s1);
    atomicAdd(ws + OFF_SUMS + bat * 2 + 1, s2);
  }
}

// ---------------- K6: LN apply + dual-K agg conv (MFMA); 1 img/block ---------
__global__ __launch_bounds__(256, 2) void k6_agg(
    const float* __restrict__ x, const float* __restrict__ gamma,
    const float* __restrict__ beta, const float* __restrict__ b_agg,
    float* __restrict__ ws, float* __restrict__ out) {
  __shared__ float alin[1600];
  __shared__ float xlin[1600];
  __shared__ u16 xta[3584];
  __shared__ u16 xtx[3584];
  __shared__ float pbuf[2][1024];
  const u16* wb = (const u16*)ws;
  int tid = threadIdx.x, lane = tid & 63, wave = tid >> 6, hi = lane >> 5;
  int img = blockIdx.x, bat = img >> 4, n = img & 15;
  int ot = wave >> 1, h = wave & 1;        // h=0: a_norm half, h=1: s half
  int oA = ot * 32 + (lane & 31);
  const u16* wsrc = wb + (h ? WAGS : WAGA) + oA * 576 + hi * 8;
  s8v A[36];
#pragma unroll
  for (int s = 0; s < 36; ++s) A[s] = *(const s8v*)(wsrc + s * 16);
  int bases[9]; mk_bases(lane, bases);
  float ssum = ws[OFF_SUMS + bat * 2], ssq = ws[OFF_SUMS + bat * 2 + 1];
  float mu = ssum * (1.f / 25600.f);
  float var = ssq * (1.f / 25600.f) - mu * mu;
  float rstd = rsqrtf(var + 1e-6f);
  for (int i = tid; i < 1792; i += 256) { ((u32*)xta)[i] = 0; ((u32*)xtx)[i] = 0; }  // each 3584 u16 ✓ full
  const float* ag = ws + OFF_A + (size_t)img * IE;
  const float* xg = x + (size_t)img * IE;
  for (int i = tid; i < 1600; i += 256) { alin[i] = ag[i]; xlin[i] = xg[i]; }
  __syncthreads();
  for (int i = tid; i < 800; i += 256) {
    int p = i >> 5, cp = i & 31;
    int e0 = cp * 50 + p, e1 = e0 + 25;
    float an0 = (alin[e0] - mu) * rstd * gamma[(size_t)n * IE + e0] + beta[(size_t)n * IE + e0];
    float an1 = (alin[e1] - mu) * rstd * gamma[(size_t)n * IE + e1] + beta[(size_t)n * IE + e1];
    xt_write_pair(xta, p, cp, an0, an1);
    xt_write_pair(xtx, p, cp, xlin[e0], xlin[e1]);
  }
  __syncthreads();
  const char* bsrc = h ? (const char*)xtx : (const char*)xta;
  f16v acc = zero16();
#pragma unroll
  for (int s = 0; s < 36; ++s) {
    s8v bfr = *(const s8v*)(bsrc + (bases[s >> 2] ^ ((s & 3) << 5)));
    acc = __builtin_amdgcn_mfma_f32_32x32x16_bf16(A[s], bfr, acc, 0, 0, 0);
  }
  int p = lane & 31;
  if (h == 1) {
#pragma unroll
    for (int r = 0; r < 16; ++r) {
      int ol = (r & 3) + 8 * (r >> 2) + 4 * hi;
      pbuf[ot][ol * 32 + p] = acc[r];
    }
  }
  __syncthreads();
  if (h == 0 && p < 25) {
#pragma unroll
    for (int r = 0; r < 16; ++r) {
      int ol = (r & 3) + 8 * (r >> 2) + 4 * hi;
      int o = ot * 32 + ol;
      float v = acc[r] + pbuf[ot][ol * 32 + p] + b_agg[o];
      out[(size_t)img * IE + o * 25 + p] = fmaxf(v, 0.f);
    }
  }
}

// ---------------- launch ----------------
extern "C" void kernel_launch(void* const* d_in, const int* in_sizes, int n_in,
                              void* d_out, int out_size, void* d_ws,
                              size_t ws_size, hipStream_t stream) {
  const float* x      = (const float*)d_in[0];
  // d_in[1] = g_idx: deterministic (i-major pairs, gate==1) — folded analytically
  const float* w_rel  = (const float*)d_in[2];
  const float* b_rel  = (const float*)d_in[3];
  const float* w_self = (const float*)d_in[4];
  const float* b_self = (const float*)d_in[5];
  const float* w_aff  = (const float*)d_in[6];
  const float* b_aff  = (const float*)d_in[7];
  const float* w_agg  = (const float*)d_in[8];
  const float* b_agg  = (const float*)d_in[9];
  const float* w_attn = (const float*)d_in[10];
  const float* b_attn = (const float*)d_in[11];
  const float* w_q    = (const float*)d_in[12];
  const float* b_q    = (const float*)d_in[13];
  const float* w_k    = (const float*)d_in[14];
  const float* b_k    = (const float*)d_in[15];
  const float* gamma  = (const float*)d_in[16];
  const float* beta   = (const float*)d_in[17];
  float* ws  = (float*)d_ws;
  float* out = (float*)d_out;

  k0_prep<<<944, 256, 0, stream>>>(w_rel, w_self, w_aff, w_agg, w_q, w_k, w_attn, ws);
  k1_qk<<<IMG / 2, 256, 0, stream>>>(x, b_attn, b_q, b_k, ws);
  k2_attn<<<64, 1024, 0, stream>>>(ws);
  k3_uvxs<<<IMG / 2, 384, 0, stream>>>(x, b_rel, b_self, ws);
  k5_pred_aff<<<IMG / 2, 256, 0, stream>>>(x, b_aff, ws);
  k6_agg<<<IMG, 256, 0, stream>>>(x, gamma, beta, b_agg, ws, out);
}